// Round 9
// baseline (152.389 us; speedup 1.0000x reference)
//
#include <hip/hip_runtime.h>
#include <hip/hip_bf16.h>

#define EPS 1e-12f
// Features stored pre-scaled by sqrt(C_EXP), C_EXP=(1/0.07)*log2(e):
// MFMA output is exp2-ready: exp(sim/T) == exp2(fs_i . fs_j).
#define SQRT_C_EXP 4.53981597f
#define M_LN2F 0.69314718056f
#define NUM_CLASSES 16
#define NC_BLOCKS 512   // norm_classsum blocks, 16 rows each

#define BM 256          // rows per denom block
#define BN 128          // cols per chunk
#define KD 128          // feature dim
#define NCHUNK 8        // col chunks per colgroup (1024 cols)
#define NCOLG 8
#define NPART 16        // colgroups(8) * wc(2)
#define NROWB 32        // 8192 / BM

typedef __attribute__((ext_vector_type(4))) float f32x4;
typedef __attribute__((ext_vector_type(8))) short bf16x8;

__device__ __forceinline__ float bf2f(ushort u) {
    unsigned int x = ((unsigned int)u) << 16;
    return __uint_as_float(x);
}

// Swizzled LDS fragment address: element (r, slot) of a [rows][128] bf16 tile,
// slot = 16B chunk within the 256B row. Swizzle: slot ^= (r&7).
__device__ __forceinline__ const bf16x8* lds_frag(const ushort* base, int r, int slot) {
    int sw = slot ^ (r & 7);
    return reinterpret_cast<const bf16x8*>(
        reinterpret_cast<const char*>(base) + r * 256 + sw * 16);
}

// ---------------- K1: normalize (pre-scaled) + class partials + ticket zero -
// 512 blocks x 256 thr; 4 waves x 4 rows. No atomics, no memset needed.
__global__ __launch_bounds__(256) void norm_classsum(
    const float* __restrict__ feat,
    const int* __restrict__ labels,
    ushort* __restrict__ fb,
    float* __restrict__ sq,
    float* __restrict__ g_part,     // [NC_BLOCKS][16][128]
    float* __restrict__ cnt_part,   // [NC_BLOCKS][16]
    int* __restrict__ tickets,      // [NROWB + 1]
    int N) {
    __shared__ float lg[4][NUM_CLASSES][128];   // 32 KB, per-wave regions
    __shared__ float lc[4][NUM_CLASSES];
    const int tid  = threadIdx.x;
    const int lane = tid & 63;
    const int w    = tid >> 6;

    if (blockIdx.x == 0 && tid < NROWB + 1) tickets[tid] = 0;

    float* myg = &lg[w][0][0];
    for (int i = lane; i < NUM_CLASSES * 128; i += 64) myg[i] = 0.f;
    if (lane < NUM_CLASSES) lc[w][lane] = 0.f;
    // each wave touches only its own region before the barrier

    const int r0 = blockIdx.x * 16 + w * 4;
    for (int rr = 0; rr < 4; rr++) {
        const int r = r0 + rr;
        const float2 v = *reinterpret_cast<const float2*>(feat + (size_t)r * KD + lane * 2);
        float s = v.x * v.x + v.y * v.y;
        #pragma unroll
        for (int off = 1; off < 64; off <<= 1) s += __shfl_xor(s, off);
        const float scale = SQRT_C_EXP / fmaxf(sqrtf(s), EPS);

        __hip_bfloat16 h0 = __float2bfloat16(v.x * scale);
        __hip_bfloat16 h1 = __float2bfloat16(v.y * scale);
        ushort u0 = *reinterpret_cast<ushort*>(&h0);
        ushort u1 = *reinterpret_cast<ushort*>(&h1);
        unsigned int pack = (unsigned int)u0 | ((unsigned int)u1 << 16);
        *reinterpret_cast<unsigned int*>(fb + (size_t)r * KD + lane * 2) = pack;

        float q0 = bf2f(u0), q1 = bf2f(u1);
        float q = q0 * q0 + q1 * q1;
        #pragma unroll
        for (int off = 1; off < 64; off <<= 1) q += __shfl_xor(q, off);
        if (lane == 0) sq[r] = q;                 // sq_s = C_EXP*||f||^2

        const int lab = labels[r];                // wave-uniform
        lg[w][lab][lane * 2]     += q0;
        lg[w][lab][lane * 2 + 1] += q1;
        if (lane == 0) lc[w][lab] += 1.f;
    }
    __syncthreads();

    const float* flat = &lg[0][0][0];
    for (int i = tid; i < NUM_CLASSES * 128; i += 256)
        g_part[(size_t)blockIdx.x * 2048 + i] =
            flat[i] + flat[2048 + i] + flat[4096 + i] + flat[6144 + i];
    if (tid < NUM_CLASSES)
        cnt_part[blockIdx.x * NUM_CLASSES + tid] =
            lc[0][tid] + lc[1][tid] + lc[2][tid] + lc[3][tid];
}

// ---------------- K2: reduce class partials ---------------------------------
// 16 blocks (one per class) x 256 threads.
__global__ void classreduce_kernel(const float* __restrict__ g_part,
                                   const float* __restrict__ cnt_part,
                                   float* __restrict__ g,
                                   float* __restrict__ cntf) {
    const int c   = blockIdx.x;
    const int tid = threadIdx.x;
    const int d   = tid & 127;
    const int seg = tid >> 7;            // 0..1
    __shared__ float tmp[2][128];
    __shared__ float sc[4];

    float acc = 0.f;
    for (int b = seg * 256; b < seg * 256 + 256; b++)
        acc += g_part[(size_t)b * 2048 + c * 128 + d];
    tmp[seg][d] = acc;

    float cv = cnt_part[tid * NUM_CLASSES + c]
             + cnt_part[(tid + 256) * NUM_CLASSES + c];
    #pragma unroll
    for (int off = 1; off < 64; off <<= 1) cv += __shfl_xor(cv, off);
    if ((tid & 63) == 0) sc[tid >> 6] = cv;
    __syncthreads();
    if (tid < 128) g[c * 128 + tid] = tmp[0][tid] + tmp[1][tid];
    if (tid == 0)  cntf[c] = sc[0] + sc[1] + sc[2] + sc[3];
}

// ---------------- K3: denom + fused rowloss + mean (ticket pattern) ---------
// Grid (8 colgroups, 32 rowblocks) = 256 blocks, 512 thr = 8 waves (4x2),
// wave tile 64x64; LDS = A 64KB + B dbuf 2x32KB = 128KB (1 block/CU).
// After denom_part writes: per-rowblock ticket -> 8th block does rowloss for
// its 256 rows; global ticket -> 32nd finisher sums blockloss in fixed order.
__global__ __launch_bounds__(512) void supcon_denom_loss(
    const ushort* __restrict__ fb,
    const int* __restrict__ labels,
    const float* __restrict__ sq,
    const float* __restrict__ g,
    const float* __restrict__ cntf,
    float* __restrict__ denom_part,   // [N][16]
    float* __restrict__ blockloss,    // [NROWB]
    int* __restrict__ tickets,        // [NROWB] + final at [NROWB]
    float* __restrict__ out,
    int N) {

    __shared__ __align__(16) ushort As[BM * KD];        // 64 KB
    __shared__ __align__(16) ushort Bs[2][BN * KD];     // 2 x 32 KB
    __shared__ int s_last;

    const int tid  = threadIdx.x;
    const int lane = tid & 63;
    const int w    = tid >> 6;        // 0..7
    const int wr   = w >> 1;          // 0..3 (64-row quadrant)
    const int wc   = w & 1;           // 0..1 (64-col half)
    const int r16  = lane & 15;
    const int g4   = lane >> 4;       // 0..3

    const int colgroup = blockIdx.x;  // 0..7
    const int rowblock = blockIdx.y;  // 0..31
    const int rowbase  = rowblock * BM;
    const int col0     = colgroup * (BN * NCHUNK);

    // ---- stage A tile (64KB) + B chunk 0 (32KB) ----
    {
        const ushort* gA = fb + (size_t)rowbase * KD;
        #pragma unroll
        for (int i = 0; i < 8; i++) {
            int c = i * 512 + tid;                  // 16B chunk index
            bf16x8 v = *reinterpret_cast<const bf16x8*>(gA + c * 8);
            int dst = c ^ ((c >> 4) & 7);
            *reinterpret_cast<bf16x8*>(&As[dst * 8]) = v;
        }
        const ushort* gB = fb + (size_t)col0 * KD;
        #pragma unroll
        for (int i = 0; i < 4; i++) {
            int c = i * 512 + tid;
            bf16x8 v = *reinterpret_cast<const bf16x8*>(gB + c * 8);
            int dst = c ^ ((c >> 4) & 7);
            *reinterpret_cast<bf16x8*>(&Bs[0][dst * 8]) = v;
        }
    }
    __syncthreads();

    float pd[4][4];
    #pragma unroll
    for (int m = 0; m < 4; m++)
        #pragma unroll
        for (int i = 0; i < 4; i++) pd[m][i] = 0.f;

    int cur = 0;
    for (int c = 0; c < NCHUNK; c++) {
        bf16x8 pre0, pre1, pre2, pre3;
        if (c + 1 < NCHUNK) {
            const ushort* gB = fb + (size_t)(col0 + (c + 1) * BN) * KD;
            pre0 = *reinterpret_cast<const bf16x8*>(gB + (0 * 512 + tid) * 8);
            pre1 = *reinterpret_cast<const bf16x8*>(gB + (1 * 512 + tid) * 8);
            pre2 = *reinterpret_cast<const bf16x8*>(gB + (2 * 512 + tid) * 8);
            pre3 = *reinterpret_cast<const bf16x8*>(gB + (3 * 512 + tid) * 8);
        }

        f32x4 acc[4][4];
        #pragma unroll
        for (int m = 0; m < 4; m++)
            #pragma unroll
            for (int n = 0; n < 4; n++) acc[m][n] = f32x4{0.f, 0.f, 0.f, 0.f};

        const ushort* bbase = Bs[cur];
        #pragma unroll
        for (int ks = 0; ks < 4; ks++) {
            const int slot = ks * 4 + g4;
            bf16x8 av[4], bv[4];
            #pragma unroll
            for (int m = 0; m < 4; m++)
                av[m] = *lds_frag(As, wr * 64 + m * 16 + r16, slot);
            #pragma unroll
            for (int n = 0; n < 4; n++)
                bv[n] = *lds_frag(bbase, wc * 64 + n * 16 + r16, slot);
            #pragma unroll
            for (int m = 0; m < 4; m++)
                #pragma unroll
                for (int n = 0; n < 4; n++)
                    acc[m][n] = __builtin_amdgcn_mfma_f32_16x16x32_bf16(av[m], bv[n], acc[m][n], 0, 0, 0);
        }

        // pre-scaled features: acc is exp2-ready
        #pragma unroll
        for (int m = 0; m < 4; m++)
            #pragma unroll
            for (int n = 0; n < 4; n++)
                #pragma unroll
                for (int i = 0; i < 4; i++)
                    pd[m][i] += __builtin_amdgcn_exp2f(acc[m][n][i]);

        if (c + 1 < NCHUNK) {
            ushort* dstb = Bs[cur ^ 1];
            int ch;
            ch = 0 * 512 + tid; *reinterpret_cast<bf16x8*>(&dstb[(ch ^ ((ch >> 4) & 7)) * 8]) = pre0;
            ch = 1 * 512 + tid; *reinterpret_cast<bf16x8*>(&dstb[(ch ^ ((ch >> 4) & 7)) * 8]) = pre1;
            ch = 2 * 512 + tid; *reinterpret_cast<bf16x8*>(&dstb[(ch ^ ((ch >> 4) & 7)) * 8]) = pre2;
            ch = 3 * 512 + tid; *reinterpret_cast<bf16x8*>(&dstb[(ch ^ ((ch >> 4) & 7)) * 8]) = pre3;
        }
        __syncthreads();
        cur ^= 1;
    }

    #pragma unroll
    for (int off = 1; off < 16; off <<= 1)
        #pragma unroll
        for (int m = 0; m < 4; m++)
            #pragma unroll
            for (int i = 0; i < 4; i++)
                pd[m][i] += __shfl_xor(pd[m][i], off);

    if (r16 == 0) {
        const int part = colgroup * 2 + wc;   // 0..15
        #pragma unroll
        for (int m = 0; m < 4; m++)
            #pragma unroll
            for (int i = 0; i < 4; i++) {
                int r = rowbase + wr * 64 + m * 16 + g4 * 4 + i;
                denom_part[(size_t)r * NPART + part] = pd[m][i];
            }
    }

    // ---- rowblock ticket: last of the 8 colgroup-blocks does rowloss ----
    __threadfence();                       // release our denom_part writes
    __syncthreads();
    if (tid == 0) {
        int old = atomicAdd(&tickets[rowblock], 1);
        s_last = (old == NCOLG - 1);
    }
    __syncthreads();
    if (!s_last) return;
    __threadfence();                       // acquire other blocks' writes

    float* lsum = (float*)As;              // reuse LDS (denom phase done)
    float wsum = 0.f;
    for (int j = 0; j < 32; j++) {
        const int r = rowbase + w * 32 + j;
        const int lab = labels[r];
        unsigned int pk = *reinterpret_cast<const unsigned int*>(fb + (size_t)r * KD + lane * 2);
        float f0 = bf2f((ushort)(pk & 0xffff));
        float f1 = bf2f((ushort)(pk >> 16));
        const float2 gv = *reinterpret_cast<const float2*>(g + lab * 128 + lane * 2);
        float p = f0 * gv.x + f1 * gv.y;   // p_s = C_EXP*(f.g)
        #pragma unroll
        for (int off = 1; off < 64; off <<= 1) p += __shfl_xor(p, off);

        float ds = (lane < NPART) ? denom_part[(size_t)r * NPART + lane] : 0.f;
        #pragma unroll
        for (int off = 1; off < NPART; off <<= 1) ds += __shfl_xor(ds, off);

        if (lane == 0) {
            float sqr    = sq[r];
            float possum = (p - sqr) * M_LN2F;
            float cnt    = cntf[lab] - 1.0f;
            float dn     = ds - __builtin_amdgcn_exp2f(sqr);
            wsum += -(possum - cnt * logf(dn + EPS)) / (cnt + EPS);
        }
    }
    if (lane == 0) lsum[w] = wsum;
    __syncthreads();
    if (tid == 0) {
        float t = 0.f;
        #pragma unroll
        for (int i = 0; i < 8; i++) t += lsum[i];
        blockloss[rowblock] = t;
        __threadfence();                   // release blockloss
        int o2 = atomicAdd(&tickets[NROWB], 1);
        if (o2 == NROWB - 1) {
            __threadfence();               // acquire all blockloss
            float tot = 0.f;
            for (int i = 0; i < NROWB; i++) tot += blockloss[i];
            out[0] = tot / (float)N;
        }
    }
}

extern "C" void kernel_launch(void* const* d_in, const int* in_sizes, int n_in,
                              void* d_out, int out_size, void* d_ws, size_t ws_size,
                              hipStream_t stream) {
    const float* feat = (const float*)d_in[0];
    const int* labels = (const int*)d_in[1];
    const int N = in_sizes[1];

    char* ws = (char*)d_ws;
    size_t off = 0;
    ushort* fb        = (ushort*)(ws + off); off += (size_t)N * KD * sizeof(ushort);
    float* sq         = (float*)(ws + off);  off += (size_t)N * sizeof(float);
    float* g_part     = (float*)(ws + off);  off += (size_t)NC_BLOCKS * NUM_CLASSES * KD * sizeof(float);
    float* cnt_part   = (float*)(ws + off);  off += (size_t)NC_BLOCKS * NUM_CLASSES * sizeof(float);
    float* g          = (float*)(ws + off);  off += (size_t)NUM_CLASSES * KD * sizeof(float);
    float* cntf       = (float*)(ws + off);  off += (size_t)NUM_CLASSES * sizeof(float);
    float* denom_part = (float*)(ws + off);  off += (size_t)N * NPART * sizeof(float);
    float* blockloss  = (float*)(ws + off);  off += (size_t)NROWB * sizeof(float);
    int*   tickets    = (int*)(ws + off);    off += (size_t)(NROWB + 1) * sizeof(int);

    norm_classsum<<<NC_BLOCKS, 256, 0, stream>>>(feat, labels, fb, sq, g_part, cnt_part, tickets, N);
    classreduce_kernel<<<NUM_CLASSES, 256, 0, stream>>>(g_part, cnt_part, g, cntf);

    dim3 grid(NCOLG, N / BM);                         // (8, 32) = 256 blocks
    supcon_denom_loss<<<grid, 512, 0, stream>>>(fb, labels, sq, g, cntf,
                                                denom_part, blockloss, tickets,
                                                (float*)d_out, N);
}

// Round 10
// 85.270 us; speedup vs baseline: 1.7871x; 1.7871x over previous
//
#include <hip/hip_runtime.h>
#include <hip/hip_bf16.h>

#define EPS 1e-12f
// Features stored pre-scaled by sqrt(C_EXP), C_EXP=(1/0.07)*log2(e):
// MFMA output is exp2-ready: exp(sim/T) == exp2(fs_i . fs_j).
#define SQRT_C_EXP 4.53981597f
#define M_LN2F 0.69314718056f
#define NUM_CLASSES 16
#define NC_BLOCKS 512   // norm_classsum blocks, 16 rows each

#define BM 256          // rows per denom block
#define BN 128          // cols per chunk
#define KD 128          // feature dim
#define NCHUNK 8        // col chunks per colgroup (1024 cols)
#define NCOLG 8
#define NPART 16        // colgroups(8) * wc(2)
#define RL_BLOCKS 128   // rowloss blocks, 64 rows each

typedef __attribute__((ext_vector_type(4))) float f32x4;
typedef __attribute__((ext_vector_type(8))) short bf16x8;

__device__ __forceinline__ float bf2f(ushort u) {
    unsigned int x = ((unsigned int)u) << 16;
    return __uint_as_float(x);
}

// Swizzled LDS fragment address: element (r, slot) of a [rows][128] bf16 tile,
// slot = 16B chunk within the 256B row. Swizzle: slot ^= (r&7).
__device__ __forceinline__ const bf16x8* lds_frag(const ushort* base, int r, int slot) {
    int sw = slot ^ (r & 7);
    return reinterpret_cast<const bf16x8*>(
        reinterpret_cast<const char*>(base) + r * 256 + sw * 16);
}

// ---------------- K1: normalize (pre-scaled) + class partials ---------------
// 512 blocks x 256 thr; 4 waves x 4 rows. No atomics, no memset needed.
__global__ __launch_bounds__(256) void norm_classsum(
    const float* __restrict__ feat,
    const int* __restrict__ labels,
    ushort* __restrict__ fb,
    float* __restrict__ sq,
    float* __restrict__ g_part,     // [NC_BLOCKS][16][128]
    float* __restrict__ cnt_part,   // [NC_BLOCKS][16]
    int N) {
    __shared__ float lg[4][NUM_CLASSES][128];   // 32 KB, per-wave regions
    __shared__ float lc[4][NUM_CLASSES];
    const int tid  = threadIdx.x;
    const int lane = tid & 63;
    const int w    = tid >> 6;

    float* myg = &lg[w][0][0];
    for (int i = lane; i < NUM_CLASSES * 128; i += 64) myg[i] = 0.f;
    if (lane < NUM_CLASSES) lc[w][lane] = 0.f;
    // each wave touches only its own region before the barrier

    const int r0 = blockIdx.x * 16 + w * 4;
    for (int rr = 0; rr < 4; rr++) {
        const int r = r0 + rr;
        const float2 v = *reinterpret_cast<const float2*>(feat + (size_t)r * KD + lane * 2);
        float s = v.x * v.x + v.y * v.y;
        #pragma unroll
        for (int off = 1; off < 64; off <<= 1) s += __shfl_xor(s, off);
        const float scale = SQRT_C_EXP / fmaxf(sqrtf(s), EPS);

        __hip_bfloat16 h0 = __float2bfloat16(v.x * scale);
        __hip_bfloat16 h1 = __float2bfloat16(v.y * scale);
        ushort u0 = *reinterpret_cast<ushort*>(&h0);
        ushort u1 = *reinterpret_cast<ushort*>(&h1);
        unsigned int pack = (unsigned int)u0 | ((unsigned int)u1 << 16);
        *reinterpret_cast<unsigned int*>(fb + (size_t)r * KD + lane * 2) = pack;

        float q0 = bf2f(u0), q1 = bf2f(u1);
        float q = q0 * q0 + q1 * q1;
        #pragma unroll
        for (int off = 1; off < 64; off <<= 1) q += __shfl_xor(q, off);
        if (lane == 0) sq[r] = q;                 // sq_s = C_EXP*||f||^2

        const int lab = labels[r];                // wave-uniform
        lg[w][lab][lane * 2]     += q0;
        lg[w][lab][lane * 2 + 1] += q1;
        if (lane == 0) lc[w][lab] += 1.f;
    }
    __syncthreads();

    const float* flat = &lg[0][0][0];
    for (int i = tid; i < NUM_CLASSES * 128; i += 256)
        g_part[(size_t)blockIdx.x * 2048 + i] =
            flat[i] + flat[2048 + i] + flat[4096 + i] + flat[6144 + i];
    if (tid < NUM_CLASSES)
        cnt_part[blockIdx.x * NUM_CLASSES + tid] =
            lc[0][tid] + lc[1][tid] + lc[2][tid] + lc[3][tid];
}

// ---------------- K2: reduce class partials ---------------------------------
// 16 blocks (one per class) x 512 threads.
__global__ void classreduce_kernel(const float* __restrict__ g_part,
                                   const float* __restrict__ cnt_part,
                                   float* __restrict__ g,
                                   float* __restrict__ cntf) {
    const int c   = blockIdx.x;
    const int tid = threadIdx.x;          // 0..511
    const int d   = tid & 127;
    const int seg = tid >> 7;             // 0..3
    __shared__ float tmp[4][128];
    __shared__ float sc[8];

    float acc = 0.f;
    for (int b = seg * 128; b < seg * 128 + 128; b++)
        acc += g_part[(size_t)b * 2048 + c * 128 + d];
    tmp[seg][d] = acc;

    float cv = cnt_part[tid * NUM_CLASSES + c];
    #pragma unroll
    for (int off = 1; off < 64; off <<= 1) cv += __shfl_xor(cv, off);
    if ((tid & 63) == 0) sc[tid >> 6] = cv;
    __syncthreads();
    if (tid < 128)
        g[c * 128 + tid] = tmp[0][tid] + tmp[1][tid] + tmp[2][tid] + tmp[3][tid];
    if (tid == 0) {
        float t = 0.f;
        #pragma unroll
        for (int i = 0; i < 8; i++) t += sc[i];
        cntf[c] = t;
    }
}

// ---------------- K3: denom partials via LDS-staged MFMA (round-5 core) -----
// 256 blocks (grid 8 colgroups x 32 rowblocks), 512 threads = 8 waves (4x2).
// Block: stage A tile (256x128, 64KB) once; loop 8 col-chunks of 128 with
// double-buffered B tile (2x32KB). XOR-swizzled LDS, one barrier/chunk.
// Pre-scaled features: acc is exp2-ready (no per-element multiply).
__global__ __launch_bounds__(512, 2) void supcon_denom(
    const ushort* __restrict__ fb,
    float* __restrict__ denom_part,
    int N) {

    __shared__ __align__(16) ushort As[BM * KD];        // 64 KB
    __shared__ __align__(16) ushort Bs[2][BN * KD];     // 2 x 32 KB

    const int tid  = threadIdx.x;
    const int lane = tid & 63;
    const int w    = tid >> 6;        // 0..7
    const int wr   = w >> 1;          // 0..3  (64-row quadrant)
    const int wc   = w & 1;           // 0..1  (64-col half)
    const int r16  = lane & 15;
    const int g4   = lane >> 4;       // 0..3

    const int rowbase = blockIdx.y * BM;
    const int col0    = blockIdx.x * (BN * NCHUNK);

    // ---- stage A tile (64KB) + B chunk 0 (32KB) ----
    {
        const ushort* gA = fb + (size_t)rowbase * KD;
        #pragma unroll
        for (int i = 0; i < 8; i++) {
            int c = i * 512 + tid;                  // 16B chunk index
            bf16x8 v = *reinterpret_cast<const bf16x8*>(gA + c * 8);
            int dst = c ^ ((c >> 4) & 7);
            *reinterpret_cast<bf16x8*>(&As[dst * 8]) = v;
        }
        const ushort* gB = fb + (size_t)col0 * KD;
        #pragma unroll
        for (int i = 0; i < 4; i++) {
            int c = i * 512 + tid;
            bf16x8 v = *reinterpret_cast<const bf16x8*>(gB + c * 8);
            int dst = c ^ ((c >> 4) & 7);
            *reinterpret_cast<bf16x8*>(&Bs[0][dst * 8]) = v;
        }
    }
    __syncthreads();

    float pd[4][4];                   // [m][i] per-row exp-sum partials
    #pragma unroll
    for (int m = 0; m < 4; m++)
        #pragma unroll
        for (int i = 0; i < 4; i++) pd[m][i] = 0.f;

    int cur = 0;
    for (int c = 0; c < NCHUNK; c++) {
        // issue next-chunk global loads early (latency hides under MFMA+exp)
        bf16x8 pre0, pre1, pre2, pre3;
        if (c + 1 < NCHUNK) {
            const ushort* gB = fb + (size_t)(col0 + (c + 1) * BN) * KD;
            pre0 = *reinterpret_cast<const bf16x8*>(gB + (0 * 512 + tid) * 8);
            pre1 = *reinterpret_cast<const bf16x8*>(gB + (1 * 512 + tid) * 8);
            pre2 = *reinterpret_cast<const bf16x8*>(gB + (2 * 512 + tid) * 8);
            pre3 = *reinterpret_cast<const bf16x8*>(gB + (3 * 512 + tid) * 8);
        }

        f32x4 acc[4][4];
        #pragma unroll
        for (int m = 0; m < 4; m++)
            #pragma unroll
            for (int n = 0; n < 4; n++) acc[m][n] = f32x4{0.f, 0.f, 0.f, 0.f};

        const ushort* bbase = Bs[cur];
        #pragma unroll
        for (int ks = 0; ks < 4; ks++) {
            const int slot = ks * 4 + g4;
            bf16x8 av[4], bv[4];
            #pragma unroll
            for (int m = 0; m < 4; m++)
                av[m] = *lds_frag(As, wr * 64 + m * 16 + r16, slot);
            #pragma unroll
            for (int n = 0; n < 4; n++)
                bv[n] = *lds_frag(bbase, wc * 64 + n * 16 + r16, slot);
            #pragma unroll
            for (int m = 0; m < 4; m++)
                #pragma unroll
                for (int n = 0; n < 4; n++)
                    acc[m][n] = __builtin_amdgcn_mfma_f32_16x16x32_bf16(av[m], bv[n], acc[m][n], 0, 0, 0);
        }

        #pragma unroll
        for (int m = 0; m < 4; m++)
            #pragma unroll
            for (int n = 0; n < 4; n++)
                #pragma unroll
                for (int i = 0; i < 4; i++)
                    pd[m][i] += __builtin_amdgcn_exp2f(acc[m][n][i]);

        if (c + 1 < NCHUNK) {
            ushort* dstb = Bs[cur ^ 1];
            int ch;
            ch = 0 * 512 + tid; *reinterpret_cast<bf16x8*>(&dstb[(ch ^ ((ch >> 4) & 7)) * 8]) = pre0;
            ch = 1 * 512 + tid; *reinterpret_cast<bf16x8*>(&dstb[(ch ^ ((ch >> 4) & 7)) * 8]) = pre1;
            ch = 2 * 512 + tid; *reinterpret_cast<bf16x8*>(&dstb[(ch ^ ((ch >> 4) & 7)) * 8]) = pre2;
            ch = 3 * 512 + tid; *reinterpret_cast<bf16x8*>(&dstb[(ch ^ ((ch >> 4) & 7)) * 8]) = pre3;
        }
        __syncthreads();
        cur ^= 1;
    }

    // reduce across the 16 lanes sharing the same rows, write partials
    #pragma unroll
    for (int off = 1; off < 16; off <<= 1)
        #pragma unroll
        for (int m = 0; m < 4; m++)
            #pragma unroll
            for (int i = 0; i < 4; i++)
                pd[m][i] += __shfl_xor(pd[m][i], off);

    if (r16 == 0) {
        const int part = blockIdx.x * 2 + wc;   // 0..15
        #pragma unroll
        for (int m = 0; m < 4; m++)
            #pragma unroll
            for (int i = 0; i < 4; i++) {
                int r = rowbase + wr * 64 + m * 16 + g4 * 4 + i;
                denom_part[(size_t)r * NPART + part] = pd[m][i];
            }
    }
}

// ---------------- K4: per-row loss -> per-block sums ------------------------
// 128 blocks x 256 thr (4 waves); each wave does 16 rows, block sums 64 rows.
__global__ __launch_bounds__(256) void rowloss_kernel(
    const ushort* __restrict__ fb,
    const int* __restrict__ labels,
    const float* __restrict__ denom_part,
    const float* __restrict__ sq,
    const float* __restrict__ g,
    const float* __restrict__ cntf,
    float* __restrict__ blockloss,
    int N) {
    __shared__ float lsum[4];
    const int tid  = threadIdx.x;
    const int lane = tid & 63;
    const int w    = tid >> 6;

    float wsum = 0.f;
    const int r0 = blockIdx.x * 64 + w * 16;
    for (int j = 0; j < 16; j++) {
        const int r = r0 + j;
        const int lab = labels[r];
        unsigned int pk = *reinterpret_cast<const unsigned int*>(fb + (size_t)r * KD + lane * 2);
        float f0 = bf2f((ushort)(pk & 0xffff));
        float f1 = bf2f((ushort)(pk >> 16));
        const float2 gv = *reinterpret_cast<const float2*>(g + lab * 128 + lane * 2);
        float p = f0 * gv.x + f1 * gv.y;          // p_s = C_EXP*(f.g)
        #pragma unroll
        for (int off = 1; off < 64; off <<= 1) p += __shfl_xor(p, off);

        float ds = (lane < NPART) ? denom_part[(size_t)r * NPART + lane] : 0.f;
        #pragma unroll
        for (int off = 1; off < NPART; off <<= 1) ds += __shfl_xor(ds, off);

        if (lane == 0) {
            float sqr    = sq[r];
            float possum = (p - sqr) * M_LN2F;
            float cnt    = cntf[lab] - 1.0f;
            float dn     = ds - __builtin_amdgcn_exp2f(sqr);
            wsum += -(possum - cnt * logf(dn + EPS)) / (cnt + EPS);
        }
    }
    if (lane == 0) lsum[w] = wsum;
    __syncthreads();
    if (tid == 0)
        blockloss[blockIdx.x] = lsum[0] + lsum[1] + lsum[2] + lsum[3];
}

// ---------------- K5: final mean over 128 block sums ------------------------
__global__ void reduce_kernel(const float* __restrict__ blockloss,
                              float* __restrict__ out, int N) {
    __shared__ float sdata[2];
    const int tid  = threadIdx.x;        // 128 threads
    const int lane = tid & 63;
    float s = blockloss[tid];
    #pragma unroll
    for (int off = 1; off < 64; off <<= 1) s += __shfl_xor(s, off);
    if (lane == 0) sdata[tid >> 6] = s;
    __syncthreads();
    if (tid == 0) out[0] = (sdata[0] + sdata[1]) / (float)N;
}

extern "C" void kernel_launch(void* const* d_in, const int* in_sizes, int n_in,
                              void* d_out, int out_size, void* d_ws, size_t ws_size,
                              hipStream_t stream) {
    const float* feat = (const float*)d_in[0];
    const int* labels = (const int*)d_in[1];
    const int N = in_sizes[1];

    char* ws = (char*)d_ws;
    size_t off = 0;
    ushort* fb        = (ushort*)(ws + off); off += (size_t)N * KD * sizeof(ushort);
    float* sq         = (float*)(ws + off);  off += (size_t)N * sizeof(float);
    float* g_part     = (float*)(ws + off);  off += (size_t)NC_BLOCKS * NUM_CLASSES * KD * sizeof(float);
    float* cnt_part   = (float*)(ws + off);  off += (size_t)NC_BLOCKS * NUM_CLASSES * sizeof(float);
    float* g          = (float*)(ws + off);  off += (size_t)NUM_CLASSES * KD * sizeof(float);
    float* cntf       = (float*)(ws + off);  off += (size_t)NUM_CLASSES * sizeof(float);
    float* denom_part = (float*)(ws + off);  off += (size_t)N * NPART * sizeof(float);
    float* blockloss  = (float*)(ws + off);  off += (size_t)RL_BLOCKS * sizeof(float);

    norm_classsum<<<NC_BLOCKS, 256, 0, stream>>>(feat, labels, fb, sq, g_part, cnt_part, N);
    classreduce_kernel<<<NUM_CLASSES, 512, 0, stream>>>(g_part, cnt_part, g, cntf);

    dim3 grid(NCOLG, N / BM);                         // (8, 32) = 256 blocks
    supcon_denom<<<grid, 512, 0, stream>>>(fb, denom_part, N);

    rowloss_kernel<<<RL_BLOCKS, 256, 0, stream>>>(fb, labels, denom_part, sq, g, cntf, blockloss, N);
    reduce_kernel<<<1, 128, 0, stream>>>(blockloss, (float*)d_out, N);
}

// Round 11
// 56.716 us; speedup vs baseline: 2.6869x; 1.5035x over previous
//
#include <hip/hip_runtime.h>
#include <hip/hip_bf16.h>

#define EPS 1e-12f
// Features stored pre-scaled by sqrt(C_EXP), C_EXP=(1/0.07)*log2(e):
// MFMA output is exp2-ready: exp(sim/T) == exp2(fs_i . fs_j).
#define SQRT_C_EXP 4.53981597f
#define M_LN2F 0.69314718056f
#define NUM_CLASSES 16
#define CS_BLOCKS 128

#define BM 256          // rows per denom block
#define BN 128          // cols per chunk
#define KD 128          // feature dim
#define NCHUNK 8        // col chunks per colgroup (1024 cols)
#define NPART 16        // denom partials per row = colgroups(8) * wc(2)

typedef __attribute__((ext_vector_type(4))) float f32x4;
typedef __attribute__((ext_vector_type(8))) short bf16x8;

__device__ __forceinline__ float bf2f(ushort u) {
    unsigned int x = ((unsigned int)u) << 16;
    return __uint_as_float(x);
}

// Swizzled LDS fragment address: element (r, slot) of a [rows][128] bf16 tile,
// slot = 16B chunk within the 256B row. Swizzle: slot ^= (r&7).
__device__ __forceinline__ const bf16x8* lds_frag(const ushort* base, int r, int slot) {
    int sw = slot ^ (r & 7);
    return reinterpret_cast<const bf16x8*>(
        reinterpret_cast<const char*>(base) + r * 256 + sw * 16);
}

// ---------------- Kernel A: L2-normalize rows -> bf16 (pre-scaled) ----------
// One wave per row; D=128 = 64 lanes x float2. sq[r] = ||fs_bf16||^2 (scaled).
__global__ void normalize_kernel(const float* __restrict__ feat,
                                 ushort* __restrict__ fb,
                                 float* __restrict__ sq,
                                 int N) {
    int r    = (blockIdx.x * blockDim.x + threadIdx.x) >> 6;
    int lane = threadIdx.x & 63;
    if (r >= N) return;
    const float2 v = *reinterpret_cast<const float2*>(feat + (size_t)r * KD + lane * 2);
    float s = v.x * v.x + v.y * v.y;
    #pragma unroll
    for (int off = 1; off < 64; off <<= 1) s += __shfl_xor(s, off);
    const float scale = SQRT_C_EXP / fmaxf(sqrtf(s), EPS);

    __hip_bfloat16 h0 = __float2bfloat16(v.x * scale);
    __hip_bfloat16 h1 = __float2bfloat16(v.y * scale);
    ushort u0 = *reinterpret_cast<ushort*>(&h0);
    ushort u1 = *reinterpret_cast<ushort*>(&h1);
    unsigned int pack = (unsigned int)u0 | ((unsigned int)u1 << 16);
    *reinterpret_cast<unsigned int*>(fb + (size_t)r * KD + lane * 2) = pack;

    float q0 = bf2f(u0), q1 = bf2f(u1);
    float q = q0 * q0 + q1 * q1;
    #pragma unroll
    for (int off = 1; off < 64; off <<= 1) q += __shfl_xor(q, off);
    if (lane == 0) sq[r] = q;                 // sq_s = C_EXP*||f||^2
}

// ---------------- Kernel A2: per-class feature sums + counts (r5 style) -----
// 128 blocks x 64 rows. Each thread owns LDS slot [half][class][col]:
// no atomics in the loop; one global atomicAdd per (class,col) per block.
__global__ __launch_bounds__(256) void classsum_kernel(
    const ushort* __restrict__ fb,
    const int* __restrict__ labels,
    float* __restrict__ g,
    float* __restrict__ cntf,
    int N) {
    __shared__ float lds[2][NUM_CLASSES][128];
    __shared__ float ldc[2][NUM_CLASSES];
    const int d    = threadIdx.x & 127;
    const int half = threadIdx.x >> 7;
    #pragma unroll
    for (int c = 0; c < NUM_CLASSES; c++) lds[half][c][d] = 0.f;
    if (d < NUM_CLASSES) ldc[half][d] = 0.f;
    __syncthreads();

    const int r0 = blockIdx.x * 64 + half * 32;
    for (int r = r0; r < r0 + 32; r++) {
        int lab = labels[r];
        lds[half][lab][d] += bf2f(fb[(size_t)r * KD + d]);
        if (d == 0) ldc[half][lab] += 1.f;
    }
    __syncthreads();

    for (int c = half; c < NUM_CLASSES; c += 2)
        atomicAdd(&g[c * KD + d], lds[0][c][d] + lds[1][c][d]);
    if (threadIdx.x < NUM_CLASSES)
        atomicAdd(&cntf[threadIdx.x], ldc[0][threadIdx.x] + ldc[1][threadIdx.x]);
}

// ---------------- Kernel B: denom partials via LDS-staged MFMA (r5 core) ----
// 256 blocks (grid 8 colgroups x 32 rowblocks), 512 threads = 8 waves (4x2).
// Stage A tile (256x128, 64KB) once; loop 8 col-chunks of 128 with
// double-buffered B (2x32KB). XOR-swizzled LDS, one barrier/chunk.
// Pre-scaled features: acc is exp2-ready (no per-element multiply).
__global__ __launch_bounds__(512, 2) void supcon_denom(
    const ushort* __restrict__ fb,
    float* __restrict__ denom_part,
    int N) {

    __shared__ __align__(16) ushort As[BM * KD];        // 64 KB
    __shared__ __align__(16) ushort Bs[2][BN * KD];     // 2 x 32 KB

    const int tid  = threadIdx.x;
    const int lane = tid & 63;
    const int w    = tid >> 6;        // 0..7
    const int wr   = w >> 1;          // 0..3  (64-row quadrant)
    const int wc   = w & 1;           // 0..1  (64-col half)
    const int r16  = lane & 15;
    const int g4   = lane >> 4;       // 0..3

    const int rowbase = blockIdx.y * BM;
    const int col0    = blockIdx.x * (BN * NCHUNK);

    // ---- stage A tile (64KB) + B chunk 0 (32KB) ----
    {
        const ushort* gA = fb + (size_t)rowbase * KD;
        #pragma unroll
        for (int i = 0; i < 8; i++) {
            int c = i * 512 + tid;                  // 16B chunk index
            bf16x8 v = *reinterpret_cast<const bf16x8*>(gA + c * 8);
            int dst = c ^ ((c >> 4) & 7);
            *reinterpret_cast<bf16x8*>(&As[dst * 8]) = v;
        }
        const ushort* gB = fb + (size_t)col0 * KD;
        #pragma unroll
        for (int i = 0; i < 4; i++) {
            int c = i * 512 + tid;
            bf16x8 v = *reinterpret_cast<const bf16x8*>(gB + c * 8);
            int dst = c ^ ((c >> 4) & 7);
            *reinterpret_cast<bf16x8*>(&Bs[0][dst * 8]) = v;
        }
    }
    __syncthreads();

    float pd[4][4];                   // [m][i] per-row exp-sum partials
    #pragma unroll
    for (int m = 0; m < 4; m++)
        #pragma unroll
        for (int i = 0; i < 4; i++) pd[m][i] = 0.f;

    int cur = 0;
    for (int c = 0; c < NCHUNK; c++) {
        // issue next-chunk global loads early (latency hides under MFMA+exp)
        bf16x8 pre0, pre1, pre2, pre3;
        if (c + 1 < NCHUNK) {
            const ushort* gB = fb + (size_t)(col0 + (c + 1) * BN) * KD;
            pre0 = *reinterpret_cast<const bf16x8*>(gB + (0 * 512 + tid) * 8);
            pre1 = *reinterpret_cast<const bf16x8*>(gB + (1 * 512 + tid) * 8);
            pre2 = *reinterpret_cast<const bf16x8*>(gB + (2 * 512 + tid) * 8);
            pre3 = *reinterpret_cast<const bf16x8*>(gB + (3 * 512 + tid) * 8);
        }

        f32x4 acc[4][4];
        #pragma unroll
        for (int m = 0; m < 4; m++)
            #pragma unroll
            for (int n = 0; n < 4; n++) acc[m][n] = f32x4{0.f, 0.f, 0.f, 0.f};

        const ushort* bbase = Bs[cur];
        #pragma unroll
        for (int ks = 0; ks < 4; ks++) {
            const int slot = ks * 4 + g4;
            bf16x8 av[4], bv[4];
            #pragma unroll
            for (int m = 0; m < 4; m++)
                av[m] = *lds_frag(As, wr * 64 + m * 16 + r16, slot);
            #pragma unroll
            for (int n = 0; n < 4; n++)
                bv[n] = *lds_frag(bbase, wc * 64 + n * 16 + r16, slot);
            #pragma unroll
            for (int m = 0; m < 4; m++)
                #pragma unroll
                for (int n = 0; n < 4; n++)
                    acc[m][n] = __builtin_amdgcn_mfma_f32_16x16x32_bf16(av[m], bv[n], acc[m][n], 0, 0, 0);
        }

        #pragma unroll
        for (int m = 0; m < 4; m++)
            #pragma unroll
            for (int n = 0; n < 4; n++)
                #pragma unroll
                for (int i = 0; i < 4; i++)
                    pd[m][i] += __builtin_amdgcn_exp2f(acc[m][n][i]);

        if (c + 1 < NCHUNK) {
            ushort* dstb = Bs[cur ^ 1];
            int ch;
            ch = 0 * 512 + tid; *reinterpret_cast<bf16x8*>(&dstb[(ch ^ ((ch >> 4) & 7)) * 8]) = pre0;
            ch = 1 * 512 + tid; *reinterpret_cast<bf16x8*>(&dstb[(ch ^ ((ch >> 4) & 7)) * 8]) = pre1;
            ch = 2 * 512 + tid; *reinterpret_cast<bf16x8*>(&dstb[(ch ^ ((ch >> 4) & 7)) * 8]) = pre2;
            ch = 3 * 512 + tid; *reinterpret_cast<bf16x8*>(&dstb[(ch ^ ((ch >> 4) & 7)) * 8]) = pre3;
        }
        __syncthreads();
        cur ^= 1;
    }

    // reduce across the 16 lanes sharing the same rows, write partials
    #pragma unroll
    for (int off = 1; off < 16; off <<= 1)
        #pragma unroll
        for (int m = 0; m < 4; m++)
            #pragma unroll
            for (int i = 0; i < 4; i++)
                pd[m][i] += __shfl_xor(pd[m][i], off);

    if (r16 == 0) {
        const int part = blockIdx.x * 2 + wc;   // 0..15
        #pragma unroll
        for (int m = 0; m < 4; m++)
            #pragma unroll
            for (int i = 0; i < 4; i++) {
                int r = rowbase + wr * 64 + m * 16 + g4 * 4 + i;
                denom_part[(size_t)r * NPART + part] = pd[m][i];
            }
    }
}

// ---------------- Kernel C: per-row loss (one wave per row) -----------------
__global__ void rowloss_kernel(const ushort* __restrict__ fb,
                               const int* __restrict__ labels,
                               const float* __restrict__ denom_part,
                               const float* __restrict__ sq,
                               const float* __restrict__ g,
                               const float* __restrict__ cntf,
                               float* __restrict__ rowloss,
                               int N) {
    int r    = (blockIdx.x * blockDim.x + threadIdx.x) >> 6;
    int lane = threadIdx.x & 63;
    if (r >= N) return;
    int lab = labels[r];
    unsigned int pk = *reinterpret_cast<const unsigned int*>(fb + (size_t)r * KD + lane * 2);
    float f0 = bf2f((ushort)(pk & 0xffff));
    float f1 = bf2f((ushort)(pk >> 16));
    const float2 gv = *reinterpret_cast<const float2*>(g + lab * KD + lane * 2);
    float p = f0 * gv.x + f1 * gv.y;          // p_s = C_EXP*(f.g)
    #pragma unroll
    for (int off = 1; off < 64; off <<= 1) p += __shfl_xor(p, off);

    float dsum = (lane < NPART) ? denom_part[(size_t)r * NPART + lane] : 0.f;
    #pragma unroll
    for (int off = 1; off < NPART; off <<= 1) dsum += __shfl_xor(dsum, off);

    if (lane == 0) {
        float sqr    = sq[r];
        float possum = (p - sqr) * M_LN2F;
        float cnt    = cntf[lab] - 1.0f;
        float dn     = dsum - __builtin_amdgcn_exp2f(sqr);  // remove diagonal
        rowloss[r]   = -(possum - cnt * logf(dn + EPS)) / (cnt + EPS);
    }
}

// ---------------- Kernel D: mean (deterministic single-block reduce) --------
__global__ void reduce_kernel(const float* __restrict__ rowloss,
                              float* __restrict__ out, int N) {
    __shared__ float sdata[16];
    float s = 0.f;
    for (int r = threadIdx.x; r < N; r += blockDim.x) s += rowloss[r];
    #pragma unroll
    for (int off = 1; off < 64; off <<= 1) s += __shfl_xor(s, off);
    int wv = threadIdx.x >> 6;
    if ((threadIdx.x & 63) == 0) sdata[wv] = s;
    __syncthreads();
    if (threadIdx.x == 0) {
        float t = 0.f;
        int nw = (int)(blockDim.x >> 6);
        for (int i = 0; i < nw; i++) t += sdata[i];
        out[0] = t / (float)N;
    }
}

extern "C" void kernel_launch(void* const* d_in, const int* in_sizes, int n_in,
                              void* d_out, int out_size, void* d_ws, size_t ws_size,
                              hipStream_t stream) {
    const float* feat = (const float*)d_in[0];
    const int* labels = (const int*)d_in[1];
    const int N = in_sizes[1];

    char* ws = (char*)d_ws;
    size_t off = 0;
    ushort* fb = (ushort*)(ws + off);                 off += (size_t)N * KD * sizeof(ushort);
    // zeroed region: g[16*128], cntf[16] (contiguous)
    float* g     = (float*)(ws + off);                off += (size_t)NUM_CLASSES * KD * sizeof(float);
    float* cntf  = (float*)(ws + off);                off += (size_t)NUM_CLASSES * sizeof(float);
    size_t zbytes = (size_t)(NUM_CLASSES * KD + NUM_CLASSES) * sizeof(float);
    // written-unconditionally: sq[N], denom_part[N*16], rowloss[N]
    float* sq         = (float*)(ws + off);           off += (size_t)N * sizeof(float);
    float* denom_part = (float*)(ws + off);           off += (size_t)N * NPART * sizeof(float);
    float* rowloss    = (float*)(ws + off);

    hipMemsetAsync(g, 0, zbytes, stream);

    normalize_kernel<<<(N + 3) / 4, 256, 0, stream>>>(feat, fb, sq, N);
    classsum_kernel<<<CS_BLOCKS, 256, 0, stream>>>(fb, labels, g, cntf, N);

    dim3 grid(N / (BN * NCHUNK), N / BM);             // (8, 32) = 256 blocks
    supcon_denom<<<grid, 512, 0, stream>>>(fb, denom_part, N);

    rowloss_kernel<<<(N + 3) / 4, 256, 0, stream>>>(fb, labels, denom_part, sq, g, cntf, rowloss, N);
    reduce_kernel<<<1, 1024, 0, stream>>>(rowloss, (float*)d_out, N);
}

// Round 12
// 50.289 us; speedup vs baseline: 3.0303x; 1.1278x over previous
//
#include <hip/hip_runtime.h>
#include <hip/hip_bf16.h>

#define EPS 1e-12f
// Features stored pre-scaled by sqrt(C_EXP), C_EXP=(1/0.07)*log2(e):
// MFMA output is exp2-ready: exp(sim/T) == exp2(fs_i . fs_j).
#define SQRT_C_EXP 4.53981597f
#define M_LN2F 0.69314718056f
#define NUM_CLASSES 16
#define CS_BLOCKS 128

#define BM 256          // rows per denom block
#define BN 128          // cols per chunk
#define KD 128          // feature dim
#define NCHUNK 8        // col chunks per colgroup (1024 cols)
#define NPART 16        // denom partials per row = colgroups(8) * wc(2)

typedef __attribute__((ext_vector_type(4))) float f32x4;
typedef __attribute__((ext_vector_type(8))) short bf16x8;

__device__ __forceinline__ float bf2f(ushort u) {
    unsigned int x = ((unsigned int)u) << 16;
    return __uint_as_float(x);
}

// Swizzled LDS fragment address: element (r, slot) of a [rows][128] bf16 tile,
// slot = 16B chunk within the 256B row. Swizzle: slot ^= (r&7).
__device__ __forceinline__ const bf16x8* lds_frag(const ushort* base, int r, int slot) {
    int sw = slot ^ (r & 7);
    return reinterpret_cast<const bf16x8*>(
        reinterpret_cast<const char*>(base) + r * 256 + sw * 16);
}

// ---------------- Kernel A: L2-normalize rows -> bf16 (pre-scaled) ----------
// One wave per row; D=128 = 64 lanes x float2. sq[r] = ||fs_bf16||^2 (scaled).
// Block 0 also zeroes g/cntf (stream order makes this visible to classsum).
__global__ void normalize_kernel(const float* __restrict__ feat,
                                 ushort* __restrict__ fb,
                                 float* __restrict__ sq,
                                 float* __restrict__ gz,   // g..cntf, 2064 floats
                                 int N) {
    if (blockIdx.x == 0) {
        for (int i = threadIdx.x; i < NUM_CLASSES * KD + NUM_CLASSES; i += 256)
            gz[i] = 0.f;
    }
    int r    = (blockIdx.x * blockDim.x + threadIdx.x) >> 6;
    int lane = threadIdx.x & 63;
    if (r >= N) return;
    const float2 v = *reinterpret_cast<const float2*>(feat + (size_t)r * KD + lane * 2);
    float s = v.x * v.x + v.y * v.y;
    #pragma unroll
    for (int off = 1; off < 64; off <<= 1) s += __shfl_xor(s, off);
    const float scale = SQRT_C_EXP / fmaxf(sqrtf(s), EPS);

    __hip_bfloat16 h0 = __float2bfloat16(v.x * scale);
    __hip_bfloat16 h1 = __float2bfloat16(v.y * scale);
    ushort u0 = *reinterpret_cast<ushort*>(&h0);
    ushort u1 = *reinterpret_cast<ushort*>(&h1);
    unsigned int pack = (unsigned int)u0 | ((unsigned int)u1 << 16);
    *reinterpret_cast<unsigned int*>(fb + (size_t)r * KD + lane * 2) = pack;

    float q0 = bf2f(u0), q1 = bf2f(u1);
    float q = q0 * q0 + q1 * q1;
    #pragma unroll
    for (int off = 1; off < 64; off <<= 1) q += __shfl_xor(q, off);
    if (lane == 0) sq[r] = q;                 // sq_s = C_EXP*||f||^2
}

// ---------------- Kernel A2: per-class feature sums + counts ----------------
// 128 blocks x 64 rows. Each thread owns LDS slot [half][class][col]:
// no atomics in the loop; one global atomicAdd per (class,col) per block.
__global__ __launch_bounds__(256) void classsum_kernel(
    const ushort* __restrict__ fb,
    const int* __restrict__ labels,
    float* __restrict__ g,
    float* __restrict__ cntf,
    int N) {
    __shared__ float lds[2][NUM_CLASSES][128];
    __shared__ float ldc[2][NUM_CLASSES];
    const int d    = threadIdx.x & 127;
    const int half = threadIdx.x >> 7;
    #pragma unroll
    for (int c = 0; c < NUM_CLASSES; c++) lds[half][c][d] = 0.f;
    if (d < NUM_CLASSES) ldc[half][d] = 0.f;
    __syncthreads();

    const int r0 = blockIdx.x * 64 + half * 32;
    for (int r = r0; r < r0 + 32; r++) {
        int lab = labels[r];
        lds[half][lab][d] += bf2f(fb[(size_t)r * KD + d]);
        if (d == 0) ldc[half][lab] += 1.f;
    }
    __syncthreads();

    for (int c = half; c < NUM_CLASSES; c += 2)
        atomicAdd(&g[c * KD + d], lds[0][c][d] + lds[1][c][d]);
    if (threadIdx.x < NUM_CLASSES)
        atomicAdd(&cntf[threadIdx.x], ldc[0][threadIdx.x] + ldc[1][threadIdx.x]);
}

// ---------------- Kernel B: denom partials via LDS-staged MFMA --------------
// 256 blocks (grid 8 colgroups x 32 rowblocks), 512 threads = 8 waves (4x2).
// Stage A tile (256x128, 64KB) once -> read A-frags into registers ONCE
// (16 x bf16x8 = 64 VGPR); loop 8 col-chunks of 128 with double-buffered B
// (2x32KB). Per chunk only B is read from LDS: 0.25 ds_reads/MFMA.
// Pre-scaled features: acc is exp2-ready (no per-element multiply).
__global__ __launch_bounds__(512, 2) void supcon_denom(
    const ushort* __restrict__ fb,
    float* __restrict__ denom_part,
    int N) {

    __shared__ __align__(16) ushort As[BM * KD];        // 64 KB
    __shared__ __align__(16) ushort Bs[2][BN * KD];     // 2 x 32 KB

    const int tid  = threadIdx.x;
    const int lane = tid & 63;
    const int w    = tid >> 6;        // 0..7
    const int wr   = w >> 1;          // 0..3  (64-row quadrant)
    const int wc   = w & 1;           // 0..1  (64-col half)
    const int r16  = lane & 15;
    const int g4   = lane >> 4;       // 0..3

    const int rowbase = blockIdx.y * BM;
    const int col0    = blockIdx.x * (BN * NCHUNK);

    // ---- stage A tile (64KB) + B chunk 0 (32KB) ----
    {
        const ushort* gA = fb + (size_t)rowbase * KD;
        #pragma unroll
        for (int i = 0; i < 8; i++) {
            int c = i * 512 + tid;                  // 16B chunk index
            bf16x8 v = *reinterpret_cast<const bf16x8*>(gA + c * 8);
            int dst = c ^ ((c >> 4) & 7);
            *reinterpret_cast<bf16x8*>(&As[dst * 8]) = v;
        }
        const ushort* gB = fb + (size_t)col0 * KD;
        #pragma unroll
        for (int i = 0; i < 4; i++) {
            int c = i * 512 + tid;
            bf16x8 v = *reinterpret_cast<const bf16x8*>(gB + c * 8);
            int dst = c ^ ((c >> 4) & 7);
            *reinterpret_cast<bf16x8*>(&Bs[0][dst * 8]) = v;
        }
    }
    __syncthreads();

    // ---- A fragments for the whole block, read from LDS once ----
    bf16x8 a[4][4];                   // [ks][m], 64 VGPR, static indexing only
    #pragma unroll
    for (int ks = 0; ks < 4; ks++) {
        const int slot = ks * 4 + g4;
        #pragma unroll
        for (int m = 0; m < 4; m++)
            a[ks][m] = *lds_frag(As, wr * 64 + m * 16 + r16, slot);
    }

    float pd[4][4];                   // [m][i] per-row exp-sum partials
    #pragma unroll
    for (int m = 0; m < 4; m++)
        #pragma unroll
        for (int i = 0; i < 4; i++) pd[m][i] = 0.f;

    int cur = 0;
    for (int c = 0; c < NCHUNK; c++) {
        // issue next-chunk global loads early (latency hides under MFMA+exp)
        bf16x8 pre0, pre1, pre2, pre3;
        if (c + 1 < NCHUNK) {
            const ushort* gB = fb + (size_t)(col0 + (c + 1) * BN) * KD;
            pre0 = *reinterpret_cast<const bf16x8*>(gB + (0 * 512 + tid) * 8);
            pre1 = *reinterpret_cast<const bf16x8*>(gB + (1 * 512 + tid) * 8);
            pre2 = *reinterpret_cast<const bf16x8*>(gB + (2 * 512 + tid) * 8);
            pre3 = *reinterpret_cast<const bf16x8*>(gB + (3 * 512 + tid) * 8);
        }

        f32x4 acc[4][4];
        #pragma unroll
        for (int m = 0; m < 4; m++)
            #pragma unroll
            for (int n = 0; n < 4; n++) acc[m][n] = f32x4{0.f, 0.f, 0.f, 0.f};

        const ushort* bbase = Bs[cur];
        #pragma unroll
        for (int ks = 0; ks < 4; ks++) {
            const int slot = ks * 4 + g4;
            bf16x8 bv[4];
            #pragma unroll
            for (int n = 0; n < 4; n++)
                bv[n] = *lds_frag(bbase, wc * 64 + n * 16 + r16, slot);
            #pragma unroll
            for (int m = 0; m < 4; m++)
                #pragma unroll
                for (int n = 0; n < 4; n++)
                    acc[m][n] = __builtin_amdgcn_mfma_f32_16x16x32_bf16(a[ks][m], bv[n], acc[m][n], 0, 0, 0);
        }

        #pragma unroll
        for (int m = 0; m < 4; m++)
            #pragma unroll
            for (int n = 0; n < 4; n++)
                #pragma unroll
                for (int i = 0; i < 4; i++)
                    pd[m][i] += __builtin_amdgcn_exp2f(acc[m][n][i]);

        if (c + 1 < NCHUNK) {
            ushort* dstb = Bs[cur ^ 1];
            int ch;
            ch = 0 * 512 + tid; *reinterpret_cast<bf16x8*>(&dstb[(ch ^ ((ch >> 4) & 7)) * 8]) = pre0;
            ch = 1 * 512 + tid; *reinterpret_cast<bf16x8*>(&dstb[(ch ^ ((ch >> 4) & 7)) * 8]) = pre1;
            ch = 2 * 512 + tid; *reinterpret_cast<bf16x8*>(&dstb[(ch ^ ((ch >> 4) & 7)) * 8]) = pre2;
            ch = 3 * 512 + tid; *reinterpret_cast<bf16x8*>(&dstb[(ch ^ ((ch >> 4) & 7)) * 8]) = pre3;
        }
        __syncthreads();
        cur ^= 1;
    }

    // reduce across the 16 lanes sharing the same rows, write partials
    #pragma unroll
    for (int off = 1; off < 16; off <<= 1)
        #pragma unroll
        for (int m = 0; m < 4; m++)
            #pragma unroll
            for (int i = 0; i < 4; i++)
                pd[m][i] += __shfl_xor(pd[m][i], off);

    if (r16 == 0) {
        const int part = blockIdx.x * 2 + wc;   // 0..15
        #pragma unroll
        for (int m = 0; m < 4; m++)
            #pragma unroll
            for (int i = 0; i < 4; i++) {
                int r = rowbase + wr * 64 + m * 16 + g4 * 4 + i;
                denom_part[(size_t)r * NPART + part] = pd[m][i];
            }
    }
}

// ---------------- Kernel C: per-row loss (one wave per row) -----------------
__global__ void rowloss_kernel(const ushort* __restrict__ fb,
                               const int* __restrict__ labels,
                               const float* __restrict__ denom_part,
                               const float* __restrict__ sq,
                               const float* __restrict__ g,
                               const float* __restrict__ cntf,
                               float* __restrict__ rowloss,
                               int N) {
    int r    = (blockIdx.x * blockDim.x + threadIdx.x) >> 6;
    int lane = threadIdx.x & 63;
    if (r >= N) return;
    int lab = labels[r];
    unsigned int pk = *reinterpret_cast<const unsigned int*>(fb + (size_t)r * KD + lane * 2);
    float f0 = bf2f((ushort)(pk & 0xffff));
    float f1 = bf2f((ushort)(pk >> 16));
    const float2 gv = *reinterpret_cast<const float2*>(g + lab * KD + lane * 2);
    float p = f0 * gv.x + f1 * gv.y;          // p_s = C_EXP*(f.g)
    #pragma unroll
    for (int off = 1; off < 64; off <<= 1) p += __shfl_xor(p, off);

    float dsum = (lane < NPART) ? denom_part[(size_t)r * NPART + lane] : 0.f;
    #pragma unroll
    for (int off = 1; off < NPART; off <<= 1) dsum += __shfl_xor(dsum, off);

    if (lane == 0) {
        float sqr    = sq[r];
        float possum = (p - sqr) * M_LN2F;
        float cnt    = cntf[lab] - 1.0f;
        float dn     = dsum - __builtin_amdgcn_exp2f(sqr);  // remove diagonal
        rowloss[r]   = -(possum - cnt * logf(dn + EPS)) / (cnt + EPS);
    }
}

// ---------------- Kernel D: mean (deterministic single-block reduce) --------
__global__ void reduce_kernel(const float* __restrict__ rowloss,
                              float* __restrict__ out, int N) {
    __shared__ float sdata[16];
    float s = 0.f;
    for (int r = threadIdx.x; r < N; r += blockDim.x) s += rowloss[r];
    #pragma unroll
    for (int off = 1; off < 64; off <<= 1) s += __shfl_xor(s, off);
    int wv = threadIdx.x >> 6;
    if ((threadIdx.x & 63) == 0) sdata[wv] = s;
    __syncthreads();
    if (threadIdx.x == 0) {
        float t = 0.f;
        int nw = (int)(blockDim.x >> 6);
        for (int i = 0; i < nw; i++) t += sdata[i];
        out[0] = t / (float)N;
    }
}

extern "C" void kernel_launch(void* const* d_in, const int* in_sizes, int n_in,
                              void* d_out, int out_size, void* d_ws, size_t ws_size,
                              hipStream_t stream) {
    const float* feat = (const float*)d_in[0];
    const int* labels = (const int*)d_in[1];
    const int N = in_sizes[1];

    char* ws = (char*)d_ws;
    size_t off = 0;
    ushort* fb = (ushort*)(ws + off);                 off += (size_t)N * KD * sizeof(ushort);
    // zeroed-by-normalize region: g[16*128], cntf[16] (contiguous)
    float* g     = (float*)(ws + off);                off += (size_t)NUM_CLASSES * KD * sizeof(float);
    float* cntf  = (float*)(ws + off);                off += (size_t)NUM_CLASSES * sizeof(float);
    // written-unconditionally: sq[N], denom_part[N*16], rowloss[N]
    float* sq         = (float*)(ws + off);           off += (size_t)N * sizeof(float);
    float* denom_part = (float*)(ws + off);           off += (size_t)N * NPART * sizeof(float);
    float* rowloss    = (float*)(ws + off);

    normalize_kernel<<<(N + 3) / 4, 256, 0, stream>>>(feat, fb, sq, g, N);
    classsum_kernel<<<CS_BLOCKS, 256, 0, stream>>>(fb, labels, g, cntf, N);

    dim3 grid(N / (BN * NCHUNK), N / BM);             // (8, 32) = 256 blocks
    supcon_denom<<<grid, 512, 0, stream>>>(fb, denom_part, N);

    rowloss_kernel<<<(N + 3) / 4, 256, 0, stream>>>(fb, labels, denom_part, sq, g, cntf, rowloss, N);
    reduce_kernel<<<1, 1024, 0, stream>>>(rowloss, (float*)d_out, N);
}